// Round 1
// baseline (967.409 us; speedup 1.0000x reference)
//
#include <hip/hip_runtime.h>

#define V_TOT 271633
#define NRR 116
#define CIN 1536   // C*D*D*D = 192*8
#define T_LEN 24
#define B_SZ 8
#define NP (NRR*NRR) // 13456
#define CATN 308     // 116 + 192

// ---------- counting sort of voxels by ROI label ----------
__global__ void zero_counts_kernel(int* counts) {
    if (threadIdx.x < 128) counts[threadIdx.x] = 0;
}

__global__ void count_kernel(const int* __restrict__ labels, int* __restrict__ counts) {
    int v = blockIdx.x * 256 + threadIdx.x;
    if (v < V_TOT) atomicAdd(&counts[labels[v]], 1);
}

__global__ void prefix_kernel(const int* __restrict__ counts, int* __restrict__ offsets,
                              int* __restrict__ cursor) {
    if (threadIdx.x == 0) {
        int acc = 0;
        for (int r = 0; r < NRR; ++r) { offsets[r] = acc; cursor[r] = acc; acc += counts[r]; }
        offsets[NRR] = acc;
    }
}

__global__ void scatter_kernel(const int* __restrict__ labels, int* __restrict__ cursor,
                               int* __restrict__ perm) {
    int v = blockIdx.x * 256 + threadIdx.x;
    if (v < V_TOT) {
        int pos = atomicAdd(&cursor[labels[v]], 1);
        perm[pos] = v;
    }
}

// ---------- Wbar[r, :] = mean over ROI r's voxels of fc_w[v, :] ----------
// grid (6, 116), block 256. Each block: one ROI x 256-column slice, register acc.
__global__ __launch_bounds__(256) void roi_reduce_w_kernel(
        const float* __restrict__ fc_w, const int* __restrict__ perm,
        const int* __restrict__ counts, const int* __restrict__ offsets,
        float* __restrict__ Wbar) {
    const int col = blockIdx.x * 256 + threadIdx.x;
    const int r = blockIdx.y;
    const int n = counts[r];
    const int off = offsets[r];
    float a0=0.f,a1=0.f,a2=0.f,a3=0.f,a4=0.f,a5=0.f,a6=0.f,a7=0.f;
    int k = 0;
    for (; k + 8 <= n; k += 8) {
        int v0 = perm[off+k+0], v1 = perm[off+k+1], v2 = perm[off+k+2], v3 = perm[off+k+3];
        int v4 = perm[off+k+4], v5 = perm[off+k+5], v6 = perm[off+k+6], v7 = perm[off+k+7];
        a0 += fc_w[(size_t)v0*CIN + col];
        a1 += fc_w[(size_t)v1*CIN + col];
        a2 += fc_w[(size_t)v2*CIN + col];
        a3 += fc_w[(size_t)v3*CIN + col];
        a4 += fc_w[(size_t)v4*CIN + col];
        a5 += fc_w[(size_t)v5*CIN + col];
        a6 += fc_w[(size_t)v6*CIN + col];
        a7 += fc_w[(size_t)v7*CIN + col];
    }
    float a = ((a0+a1)+(a2+a3)) + ((a4+a5)+(a6+a7));
    for (; k < n; ++k) a += fc_w[(size_t)perm[off+k]*CIN + col];
    Wbar[r*CIN + col] = a / (float)n;
}

// bbar[r] = mean over ROI r of fc_b[v]. grid 116, block 64.
__global__ void roi_reduce_b_kernel(const float* __restrict__ fc_b, const int* __restrict__ perm,
                                    const int* __restrict__ counts, const int* __restrict__ offsets,
                                    float* __restrict__ bbar) {
    int r = blockIdx.x;
    int n = counts[r], off = offsets[r];
    float a = 0.f;
    for (int k = threadIdx.x; k < n; k += 64) a += fc_b[perm[off+k]];
    for (int s = 32; s > 0; s >>= 1) a += __shfl_down(a, s);
    if (threadIdx.x == 0) bbar[r] = a / (float)n;
}

// ---------- xbar[b,i] = mean_t x[b,i,t] ----------
__global__ void xbar_kernel(const float* __restrict__ x, float* __restrict__ xbar) {
    int idx = blockIdx.x * 256 + threadIdx.x;
    if (idx < B_SZ * CIN) {
        const float* p = x + (size_t)idx * T_LEN;
        float s = 0.f;
        #pragma unroll
        for (int t = 0; t < T_LEN; ++t) s += p[t];
        xbar[idx] = s * (1.0f / T_LEN);
    }
}

// ---------- x_node[b,r] = xbar[b,:] . Wbar[r,:] + bbar[r] ----------
// grid 116, block 256 (4 waves, each wave handles 2 b's)
__global__ void x_node_kernel(const float* __restrict__ xbar, const float* __restrict__ Wbar,
                              const float* __restrict__ bbar, float* __restrict__ x_node) {
    int r = blockIdx.x;
    int lane = threadIdx.x & 63, w = threadIdx.x >> 6;
    const float* wr = Wbar + r * CIN;
    for (int b = w; b < B_SZ; b += 4) {
        const float* xb = xbar + b * CIN;
        float s = 0.f;
        for (int i = lane; i < CIN; i += 64) s += xb[i] * wr[i];
        for (int sft = 32; sft > 0; sft >>= 1) s += __shfl_down(s, sft);
        if (lane == 0) x_node[b * NRR + r] = s + bbar[r];
    }
}

// ---------- per-ROI tiny MLPs: one wave per (b, r) ----------
// grid 232, block 256  (232*4 = 928 = 8*116 waves)
__global__ void fs_mlp_kernel(const float* __restrict__ x_node,
                              const float* __restrict__ w1, const float* __restrict__ b1,
                              const float* __restrict__ w2, const float* __restrict__ b2,
                              const float* __restrict__ w3, const float* __restrict__ b3,
                              float* __restrict__ fx) {
    int w = blockIdx.x * 4 + (threadIdx.x >> 6);
    int lane = threadIdx.x & 63;
    int b = w / NRR, r = w % NRR;
    float xn = x_node[b * NRR + r];
    float h1 = fmaxf(xn * w1[r*64 + lane] + b1[r*64 + lane], 0.f);
    const float* w2row = w2 + ((size_t)r*64 + lane) * 64;
    float acc = b2[r*64 + lane];
    #pragma unroll
    for (int i = 0; i < 64; ++i) acc += __shfl(h1, i) * w2row[i];
    float h2 = fmaxf(acc, 0.f);
    float p = h2 * w3[r*64 + lane];
    for (int s = 32; s > 0; s >>= 1) p += __shfl_down(p, s);
    if (lane == 0) fx[b * NRR + r] = p + b3[r];
}

// ---------- distance MLP: one wave per pair p ----------
// grid 3364, block 256 (3364*4 = 13456 waves)
__global__ void dist_mlp_kernel(const float* __restrict__ dist,
                                const float* __restrict__ mw1, const float* __restrict__ mb1,
                                const float* __restrict__ mw2, const float* __restrict__ mb2,
                                const float* __restrict__ mw3, const float* __restrict__ mb3,
                                float* __restrict__ md) {
    int p = blockIdx.x * 4 + (threadIdx.x >> 6);
    int lane = threadIdx.x & 63;
    float d = dist[p];
    float g1 = fmaxf(d * mw1[lane] + mb1[lane], 0.f);
    const float* w2row = mw2 + lane * 64;
    float acc = mb2[lane];
    #pragma unroll
    for (int i = 0; i < 64; ++i) acc += __shfl(g1, i) * w2row[i];
    float g2 = fmaxf(acc, 0.f);
    float t = g2 * mw3[lane];
    for (int s = 32; s > 0; s >>= 1) t += __shfl_down(t, s);
    if (lane == 0) md[p] = t + mb3[0];
}

// ---------- mmat[j] = fc1_w[j,:] . md + fc1_b[j], j<64 ----------
__global__ void fc1_kernel(const float* __restrict__ fc1_w, const float* __restrict__ fc1_b,
                           const float* __restrict__ md, float* __restrict__ mmat) {
    int j = blockIdx.x;
    const float* row = fc1_w + (size_t)j * NP;
    float s = 0.f;
    for (int p = threadIdx.x; p < NP; p += 256) s += row[p] * md[p];
    __shared__ float red[4];
    for (int sft = 32; sft > 0; sft >>= 1) s += __shfl_down(s, sft);
    if ((threadIdx.x & 63) == 0) red[threadIdx.x >> 6] = s;
    __syncthreads();
    if (threadIdx.x == 0) mmat[j] = red[0] + red[1] + red[2] + red[3] + fc1_b[j];
}

// ---------- mf + pooled -> cat[8][308] ----------
__global__ void tail_a_kernel(const float* __restrict__ mmat, const float* __restrict__ fx,
                              const float* __restrict__ xbar, float* __restrict__ cat) {
    for (int idx = threadIdx.x; idx < B_SZ * NRR; idx += 256) {
        int b = idx / NRR, r = idx % NRR;
        float s = 0.f;
        #pragma unroll
        for (int k = 0; k < 8; ++k) s += mmat[b*8 + k] * fx[k * NRR + r];
        cat[b * CATN + r] = s;
    }
    for (int idx = threadIdx.x; idx < B_SZ * 192; idx += 256) {
        int b = idx / 192, c = idx % 192;
        float s = 0.f;
        #pragma unroll
        for (int j = 0; j < 8; ++j) s += xbar[b * CIN + c*8 + j];
        cat[b * CATN + NRR + c] = s * (1.0f / 8.0f);
    }
}

// ---------- weff[k] = sum_j hidden_w[j,k]*out_w[j]; weff[308] = beff ----------
__global__ void weff_kernel(const float* __restrict__ hidden_w, const float* __restrict__ hidden_b,
                            const float* __restrict__ out_w, const float* __restrict__ out_b,
                            float* __restrict__ weff) {
    int k = blockIdx.x * 256 + threadIdx.x;
    if (k < CATN) {
        float s = 0.f;
        for (int j = 0; j < 768; ++j) s += hidden_w[(size_t)j * CATN + k] * out_w[j];
        weff[k] = s;
    } else if (k == CATN) {
        float s = 0.f;
        for (int j = 0; j < 768; ++j) s += hidden_b[j] * out_w[j];
        weff[CATN] = s + out_b[0];
    }
}

// ---------- out[b] = cat[b,:] . weff + beff ---------- block 512 = 8 waves
__global__ void out_kernel(const float* __restrict__ cat, const float* __restrict__ weff,
                           float* __restrict__ out) {
    int b = threadIdx.x >> 6, lane = threadIdx.x & 63;
    float s = 0.f;
    for (int k = lane; k < CATN; k += 64) s += cat[b * CATN + k] * weff[k];
    for (int sft = 32; sft > 0; sft >>= 1) s += __shfl_down(s, sft);
    if (lane == 0) out[b] = s + weff[CATN];
}

extern "C" void kernel_launch(void* const* d_in, const int* in_sizes, int n_in,
                              void* d_out, int out_size, void* d_ws, size_t ws_size,
                              hipStream_t stream) {
    const float* x        = (const float*)d_in[0];
    const int*   labels   = (const int*)d_in[1];
    const float* dist     = (const float*)d_in[2];
    const float* fc_w     = (const float*)d_in[3];
    const float* fc_b     = (const float*)d_in[4];
    const float* fs_w1    = (const float*)d_in[5];
    const float* fs_b1    = (const float*)d_in[6];
    const float* fs_w2    = (const float*)d_in[7];
    const float* fs_b2    = (const float*)d_in[8];
    const float* fs_w3    = (const float*)d_in[9];
    const float* fs_b3    = (const float*)d_in[10];
    const float* m_w1     = (const float*)d_in[11];
    const float* m_b1     = (const float*)d_in[12];
    const float* m_w2     = (const float*)d_in[13];
    const float* m_b2     = (const float*)d_in[14];
    const float* m_w3     = (const float*)d_in[15];
    const float* m_b3     = (const float*)d_in[16];
    const float* fc1_w    = (const float*)d_in[17];
    const float* fc1_b    = (const float*)d_in[18];
    const float* hidden_w = (const float*)d_in[19];
    const float* hidden_b = (const float*)d_in[20];
    const float* out_w    = (const float*)d_in[21];
    const float* out_b    = (const float*)d_in[22];
    float* out = (float*)d_out;

    // workspace layout
    int* counts  = (int*)d_ws;           // 128
    int* offsets = counts + 128;         // 128 (offsets[116] = V)
    int* cursor  = offsets + 128;        // 128
    int* perm    = cursor + 128;         // V_TOT
    float* fb = (float*)(perm + ((V_TOT + 255) / 256) * 256);
    float* Wbar   = fb;  fb += NRR * CIN;     // 178176
    float* bbar   = fb;  fb += 128;
    float* xbar   = fb;  fb += B_SZ * CIN;    // 12288
    float* x_node = fb;  fb += B_SZ * NRR;
    float* fx     = fb;  fb += B_SZ * NRR;
    float* md     = fb;  fb += NP;
    float* mmat   = fb;  fb += 64;
    float* cat    = fb;  fb += B_SZ * CATN;
    float* weff   = fb;  fb += 320;

    const int vblocks = (V_TOT + 255) / 256;

    zero_counts_kernel<<<1, 128, 0, stream>>>(counts);
    count_kernel<<<vblocks, 256, 0, stream>>>(labels, counts);
    prefix_kernel<<<1, 64, 0, stream>>>(counts, offsets, cursor);
    scatter_kernel<<<vblocks, 256, 0, stream>>>(labels, cursor, perm);
    roi_reduce_w_kernel<<<dim3(6, NRR), 256, 0, stream>>>(fc_w, perm, counts, offsets, Wbar);
    roi_reduce_b_kernel<<<NRR, 64, 0, stream>>>(fc_b, perm, counts, offsets, bbar);
    xbar_kernel<<<(B_SZ * CIN + 255) / 256, 256, 0, stream>>>(x, xbar);
    x_node_kernel<<<NRR, 256, 0, stream>>>(xbar, Wbar, bbar, x_node);
    fs_mlp_kernel<<<232, 256, 0, stream>>>(x_node, fs_w1, fs_b1, fs_w2, fs_b2, fs_w3, fs_b3, fx);
    dist_mlp_kernel<<<NP / 4, 256, 0, stream>>>(dist, m_w1, m_b1, m_w2, m_b2, m_w3, m_b3, md);
    fc1_kernel<<<64, 256, 0, stream>>>(fc1_w, fc1_b, md, mmat);
    tail_a_kernel<<<1, 256, 0, stream>>>(mmat, fx, xbar, cat);
    weff_kernel<<<2, 256, 0, stream>>>(hidden_w, hidden_b, out_w, out_b, weff);
    out_kernel<<<1, 512, 0, stream>>>(cat, weff, out);
}